// Round 1
// baseline (457.996 us; speedup 1.0000x reference)
//
#include <hip/hip_runtime.h>
#include <math.h>

#define LSEQ 4096
#define D_IN 8
#define D_MODEL 256
#define ED 512
#define NSTATE 16
#define KCONV 4
#define DT_RANK 16
#define EPS 1e-5f
#define NCHUNK 64
#define CHUNK 64   /* LSEQ / NCHUNK */

__device__ __forceinline__ float sigmoidf_(float x){ return 1.f/(1.f+__expf(-x)); }
__device__ __forceinline__ float siluf_(float x){ return x*sigmoidf_(x); }
__device__ __forceinline__ float softplusf_(float x){
  return (x > 20.f) ? x : log1pf(__expf(x));
}

// h[t][d] = x[t][:] . fc_in_w[d][:] + fc_in_b[d]
__global__ void k_fc_in(const float* __restrict__ x, const float* __restrict__ w,
                        const float* __restrict__ b, float* __restrict__ h) {
  int idx = blockIdx.x*256 + threadIdx.x;   // t*256 + d
  int t = idx >> 8, d = idx & 255;
  float acc = b[d];
#pragma unroll
  for (int i = 0; i < D_IN; ++i) acc += x[t*D_IN+i]*w[d*D_IN+i];
  h[idx] = acc;
}

// invrms[t] = rsqrt(mean(h[t]^2)+eps) — one wave per row
__global__ void k_rms(const float* __restrict__ h, float* __restrict__ invrms){
  int wave = threadIdx.x >> 6, lane = threadIdx.x & 63;
  int row = blockIdx.x*4 + wave;
  const float4 v = *(const float4*)&h[row*D_MODEL + lane*4];
  float s = v.x*v.x + v.y*v.y + v.z*v.z + v.w*v.w;
#pragma unroll
  for (int m = 32; m; m >>= 1) s += __shfl_xor(s, m);
  if (lane == 0) invrms[row] = rsqrtf(s*(1.f/D_MODEL) + EPS);
}

// C[M x N] = op(A)[M x K] @ B[N x K]^T ; RMS: A'[m][k]=A[m][k]*rowScale[m]*colScale[k]
// ACC: C += result (residual). BM=BN=64, BK=32, 256 threads, 4x4 microtile.
template<bool RMS, bool ACC>
__global__ __launch_bounds__(256) void k_gemm_abt(
    const float* __restrict__ A, const float* __restrict__ B, float* __restrict__ C,
    int M, int N, int K,
    const float* __restrict__ rowScale, const float* __restrict__ colScale)
{
  constexpr int BM_=64, BN_=64, BK_=32;
  __shared__ float As[BK_][BM_+4];
  __shared__ float Bs[BK_][BN_+4];
  int tid = threadIdx.x;
  int bm = blockIdx.x*BM_;
  int bn = blockIdx.y*BN_;
  int tx = tid & 15, ty = tid >> 4;
  float acc[4][4] = {};
  for (int k0 = 0; k0 < K; k0 += BK_) {
#pragma unroll
    for (int j = 0; j < 2; ++j) {
      int idx = tid*2 + j;          // 0..511 float4 slots
      int r  = idx >> 3;            // 0..63 tile row
      int kk = (idx & 7) << 2;      // 0..28
      float4 v = *(const float4*)&A[(size_t)(bm+r)*K + k0 + kk];
      if (RMS) {
        float rs = rowScale[bm+r];
        v.x *= rs*colScale[k0+kk+0];
        v.y *= rs*colScale[k0+kk+1];
        v.z *= rs*colScale[k0+kk+2];
        v.w *= rs*colScale[k0+kk+3];
      }
      As[kk+0][r]=v.x; As[kk+1][r]=v.y; As[kk+2][r]=v.z; As[kk+3][r]=v.w;
      float4 w = make_float4(0.f,0.f,0.f,0.f);
      if (bn + r < N) w = *(const float4*)&B[(size_t)(bn+r)*K + k0 + kk];
      Bs[kk+0][r]=w.x; Bs[kk+1][r]=w.y; Bs[kk+2][r]=w.z; Bs[kk+3][r]=w.w;
    }
    __syncthreads();
#pragma unroll
    for (int k = 0; k < BK_; ++k) {
      const float4 a = *(const float4*)&As[k][ty*4];
      const float4 b = *(const float4*)&Bs[k][tx*4];
      float av[4] = {a.x,a.y,a.z,a.w};
      float bv[4] = {b.x,b.y,b.z,b.w};
#pragma unroll
      for (int i = 0; i < 4; ++i)
#pragma unroll
        for (int jj = 0; jj < 4; ++jj)
          acc[i][jj] += av[i]*bv[jj];
    }
    __syncthreads();
  }
#pragma unroll
  for (int i = 0; i < 4; ++i) {
    int row = bm + ty*4 + i;
#pragma unroll
    for (int jj = 0; jj < 4; ++jj) {
      int col = bn + tx*4 + jj;
      if (col < N) {
        size_t o = (size_t)row*N + col;
        C[o] = ACC ? (C[o] + acc[i][jj]) : acc[i][jj];
      }
    }
  }
}

// xc[t][e] = silu( sum_k xi[t-3+k][e]*cw[e][k] + cb[e] ), xi = xz[:, :ED]
__global__ void k_conv(const float* __restrict__ xz, const float* __restrict__ cw,
                       const float* __restrict__ cb, float* __restrict__ xc){
  int idx = blockIdx.x*256 + threadIdx.x;  // t*512+e
  int t = idx >> 9, e = idx & 511;
  float acc = cb[e];
#pragma unroll
  for (int k = 0; k < KCONV; ++k) {
    int ts = t - (KCONV-1) + k;
    if (ts >= 0) acc += xz[ts*(2*ED) + e] * cw[e*KCONV + k];
  }
  xc[idx] = siluf_(acc);
}

// delta[t][e] = softplus( dbc[t][:16] . dtw[e][:] + dtb[e] )
__global__ void k_dtproj(const float* __restrict__ dbc, const float* __restrict__ dtw,
                         const float* __restrict__ dtb, float* __restrict__ delta){
  __shared__ float row[DT_RANK];
  int t = blockIdx.x >> 1;
  int e = (blockIdx.x & 1)*256 + threadIdx.x;
  if (threadIdx.x < DT_RANK) row[threadIdx.x] = dbc[t*48 + threadIdx.x];
  __syncthreads();
  float acc = dtb[e];
#pragma unroll
  for (int r = 0; r < DT_RANK; ++r) acc += row[r]*dtw[e*DT_RANK+r];
  delta[t*ED+e] = softplusf_(acc);
}

// Phase 1: per chunk c, per e: S[c][e]=sum delta ; Q[c][n][e]= local scan end (h0=0)
__global__ void k_scan1(const float* __restrict__ delta, const float* __restrict__ xc,
                        const float* __restrict__ dbc, const float* __restrict__ alog,
                        float* __restrict__ S, float* __restrict__ Q){
  __shared__ float Bs[CHUNK][NSTATE];
  int c = blockIdx.x >> 1;
  int e = (blockIdx.x & 1)*256 + threadIdx.x;
  int t0 = c*CHUNK;
  for (int i = threadIdx.x; i < CHUNK*NSTATE; i += 256) {
    int t = i >> 4, n = i & 15;
    Bs[t][n] = dbc[(t0+t)*48 + DT_RANK + n];
  }
  __syncthreads();
  float A[NSTATE];
#pragma unroll
  for (int n = 0; n < NSTATE; ++n) A[n] = -__expf(alog[e*NSTATE+n]);
  float h[NSTATE] = {};
  float sd = 0.f;
  for (int t = 0; t < CHUNK; ++t) {
    float d   = delta[(t0+t)*ED + e];
    float xcv = xc[(t0+t)*ED + e];
    sd += d;
    float dx = d*xcv;
#pragma unroll
    for (int n = 0; n < NSTATE; ++n)
      h[n] = __expf(d*A[n])*h[n] + dx*Bs[t][n];
  }
  S[c*ED + e] = sd;
#pragma unroll
  for (int n = 0; n < NSTATE; ++n) Q[(c*NSTATE+n)*ED + e] = h[n];
}

// Phase 2: sequential over chunks, parallel over 8192 (n,e) channels.
// Hin[c] = state BEFORE chunk c.
__global__ void k_scan2(const float* __restrict__ alog, const float* __restrict__ S,
                        const float* __restrict__ Q, float* __restrict__ Hin){
  int ch = blockIdx.x*256 + threadIdx.x;  // n*512 + e
  int n = ch >> 9, e = ch & 511;
  float a = -__expf(alog[e*NSTATE+n]);
  float h = 0.f;
  for (int c = 0; c < NCHUNK; ++c) {
    Hin[(c*NSTATE+n)*ED + e] = h;
    h = __expf(a*S[c*ED+e])*h + Q[(c*NSTATE+n)*ED + e];
  }
}

// Phase 3: replay chunk with true Hin; fuse C-dot, D-skip and silu(z) gate.
__global__ void k_scan3(const float* __restrict__ delta, const float* __restrict__ xc,
                        const float* __restrict__ dbc, const float* __restrict__ alog,
                        const float* __restrict__ Hin, const float* __restrict__ xz,
                        const float* __restrict__ Dv, float* __restrict__ y){
  __shared__ float Bs[CHUNK][NSTATE];
  __shared__ float Cs[CHUNK][NSTATE];
  int c = blockIdx.x >> 1;
  int e = (blockIdx.x & 1)*256 + threadIdx.x;
  int t0 = c*CHUNK;
  for (int i = threadIdx.x; i < CHUNK*NSTATE; i += 256) {
    int t = i >> 4, n = i & 15;
    Bs[t][n] = dbc[(t0+t)*48 + DT_RANK + n];
    Cs[t][n] = dbc[(t0+t)*48 + DT_RANK + NSTATE + n];
  }
  __syncthreads();
  float A[NSTATE], h[NSTATE];
#pragma unroll
  for (int n = 0; n < NSTATE; ++n) {
    A[n] = -__expf(alog[e*NSTATE+n]);
    h[n] = Hin[(c*NSTATE+n)*ED + e];
  }
  float dv = Dv[e];
  for (int t = 0; t < CHUNK; ++t) {
    float d   = delta[(t0+t)*ED + e];
    float xcv = xc[(t0+t)*ED + e];
    float dx = d*xcv;
    float ysum = 0.f;
#pragma unroll
    for (int n = 0; n < NSTATE; ++n) {
      h[n] = __expf(d*A[n])*h[n] + dx*Bs[t][n];
      ysum += h[n]*Cs[t][n];
    }
    float zv = xz[(t0+t)*(2*ED) + ED + e];
    y[(t0+t)*ED + e] = (ysum + dv*xcv) * siluf_(zv);
  }
}

// out[t] = tanh( h[t][:] . fc_out_w + fc_out_b ) — one wave per row
__global__ void k_fc_out(const float* __restrict__ h, const float* __restrict__ w,
                         const float* __restrict__ b, float* __restrict__ out){
  int wave = threadIdx.x >> 6, lane = threadIdx.x & 63;
  int row = blockIdx.x*4 + wave;
  const float4 hv = *(const float4*)&h[row*D_MODEL + lane*4];
  const float4 wv = *(const float4*)&w[lane*4];
  float s = hv.x*wv.x + hv.y*wv.y + hv.z*wv.z + hv.w*wv.w;
#pragma unroll
  for (int m = 32; m; m >>= 1) s += __shfl_xor(s, m);
  if (lane == 0) out[row] = tanhf(s + b[0]);
}

extern "C" void kernel_launch(void* const* d_in, const int* in_sizes, int n_in,
                              void* d_out, int out_size, void* d_ws, size_t ws_size,
                              hipStream_t stream){
  const float* x    = (const float*)d_in[0];
  const float* fiw  = (const float*)d_in[1];
  const float* fib  = (const float*)d_in[2];
  const float* fow  = (const float*)d_in[3];
  const float* fob  = (const float*)d_in[4];
  const float* nw   = (const float*)d_in[5];
  const float* ipw  = (const float*)d_in[6];
  const float* cw   = (const float*)d_in[7];
  const float* cb   = (const float*)d_in[8];
  const float* xpw  = (const float*)d_in[9];
  const float* dtw  = (const float*)d_in[10];
  const float* dtb  = (const float*)d_in[11];
  const float* alog = (const float*)d_in[12];
  const float* Dv   = (const float*)d_in[13];
  const float* opw  = (const float*)d_in[14];

  float* W = (float*)d_ws;
  float* h      = W;                                  // L*256
  float* invrms = h      + (size_t)LSEQ*D_MODEL;      // L
  float* xz     = invrms + LSEQ;                      // L*1024
  float* xc     = xz     + (size_t)LSEQ*2*ED;         // L*512
  float* dbc    = xc     + (size_t)LSEQ*ED;           // L*48
  float* delta  = dbc    + (size_t)LSEQ*48;           // L*512
  float* S      = delta  + (size_t)LSEQ*ED;           // 64*512
  float* Q      = S      + (size_t)NCHUNK*ED;         // 64*16*512
  float* Hin    = Q      + (size_t)NCHUNK*NSTATE*ED;  // 64*16*512
  float* y      = Hin    + (size_t)NCHUNK*NSTATE*ED;  // L*512

  k_fc_in<<<LSEQ*D_MODEL/256, 256, 0, stream>>>(x, fiw, fib, h);

  for (int l = 0; l < 2; ++l) {
    const float* nw_l   = nw   + l*D_MODEL;
    const float* ipw_l  = ipw  + (size_t)l*2*ED*D_MODEL;
    const float* cw_l   = cw   + l*ED*KCONV;
    const float* cb_l   = cb   + l*ED;
    const float* xpw_l  = xpw  + (size_t)l*48*ED;
    const float* dtw_l  = dtw  + l*ED*DT_RANK;
    const float* dtb_l  = dtb  + l*ED;
    const float* alog_l = alog + l*ED*NSTATE;
    const float* D_l    = Dv   + l*ED;
    const float* opw_l  = opw  + (size_t)l*D_MODEL*ED;

    k_rms<<<LSEQ/4, 256, 0, stream>>>(h, invrms);
    k_gemm_abt<true ,false><<<dim3(LSEQ/64, (2*ED)/64), 256, 0, stream>>>(
        h, ipw_l, xz, LSEQ, 2*ED, D_MODEL, invrms, nw_l);
    k_conv<<<LSEQ*ED/256, 256, 0, stream>>>(xz, cw_l, cb_l, xc);
    k_gemm_abt<false,false><<<dim3(LSEQ/64, 1), 256, 0, stream>>>(
        xc, xpw_l, dbc, LSEQ, 48, ED, nullptr, nullptr);
    k_dtproj<<<LSEQ*2, 256, 0, stream>>>(dbc, dtw_l, dtb_l, delta);
    k_scan1<<<NCHUNK*2, 256, 0, stream>>>(delta, xc, dbc, alog_l, S, Q);
    k_scan2<<<ED*NSTATE/256, 256, 0, stream>>>(alog_l, S, Q, Hin);
    k_scan3<<<NCHUNK*2, 256, 0, stream>>>(delta, xc, dbc, alog_l, Hin, xz, D_l, y);
    k_gemm_abt<false,true ><<<dim3(LSEQ/64, D_MODEL/64), 256, 0, stream>>>(
        y, opw_l, h, LSEQ, D_MODEL, ED, nullptr, nullptr);
  }

  k_fc_out<<<LSEQ/4, 256, 0, stream>>>(h, fow, fob, (float*)d_out);
}

// Round 2
// 245.792 us; speedup vs baseline: 1.8633x; 1.8633x over previous
//
#include <hip/hip_runtime.h>
#include <math.h>

#define LSEQ 4096
#define D_IN 8
#define D_MODEL 256
#define ED 512
#define NSTATE 16
#define KCONV 4
#define DT_RANK 16
#define EPS 1e-5f
#define NCHUNK 256
#define CHUNK 16   /* LSEQ / NCHUNK */

typedef short short8 __attribute__((ext_vector_type(8)));
typedef unsigned short ushort8 __attribute__((ext_vector_type(8)));
typedef unsigned short ushort4v __attribute__((ext_vector_type(4)));
typedef float f32x4 __attribute__((ext_vector_type(4)));

__device__ __forceinline__ float sigmoidf_(float x){ return 1.f/(1.f+__expf(-x)); }
__device__ __forceinline__ float siluf_(float x){ return x*sigmoidf_(x); }
__device__ __forceinline__ float softplusf_(float x){
  return (x > 20.f) ? x : log1pf(__expf(x));
}
// float -> bf16 bits, round-to-nearest-even
__device__ __forceinline__ unsigned short f2bf(float f){
  unsigned int u = __float_as_uint(f);
  return (unsigned short)((u + 0x7fffu + ((u>>16)&1u)) >> 16);
}

// ---- weight conversion (once per launch) ----
__global__ void k_wconv(const float* __restrict__ ipw, const float* __restrict__ xpw,
                        const float* __restrict__ opw, unsigned short* __restrict__ wip,
                        unsigned short* __restrict__ wxp, unsigned short* __restrict__ wop){
  int i = blockIdx.x*256 + threadIdx.x;           // 0 .. 524287
  wip[i] = f2bf(ipw[i]);
  if (i < 2*48*ED)      wxp[i] = f2bf(xpw[i]);
  if (i < 2*D_MODEL*ED) wop[i] = f2bf(opw[i]);
}

// h[t][d] = x[t][:] . fc_in_w[d][:] + fc_in_b[d]
__global__ void k_fc_in(const float* __restrict__ x, const float* __restrict__ w,
                        const float* __restrict__ b, float* __restrict__ h) {
  int idx = blockIdx.x*256 + threadIdx.x;   // t*256 + d
  int t = idx >> 8, d = idx & 255;
  float acc = b[d];
#pragma unroll
  for (int i = 0; i < D_IN; ++i) acc += x[t*D_IN+i]*w[d*D_IN+i];
  h[idx] = acc;
}

// xn[t][d] = bf16( h[t][d] * rsqrt(mean h^2 + eps) * nw[d] ) — one wave per row
__global__ void k_rmsapply(const float* __restrict__ h, const float* __restrict__ nw,
                           unsigned short* __restrict__ xn){
  int wave = threadIdx.x >> 6, lane = threadIdx.x & 63;
  int row = blockIdx.x*4 + wave;
  const float4 v = *(const float4*)&h[row*D_MODEL + lane*4];
  float s = v.x*v.x + v.y*v.y + v.z*v.z + v.w*v.w;
#pragma unroll
  for (int m = 32; m; m >>= 1) s += __shfl_xor(s, m);
  float inv = rsqrtf(s*(1.f/D_MODEL) + EPS);
  const float4 w4 = *(const float4*)&nw[lane*4];
  ushort4v o;
  o.x = f2bf(v.x*inv*w4.x); o.y = f2bf(v.y*inv*w4.y);
  o.z = f2bf(v.z*inv*w4.z); o.w = f2bf(v.w*inv*w4.w);
  *(ushort4v*)&xn[row*D_MODEL + lane*4] = o;
}

// ---- bf16 MFMA GEMM: C[MxN] (+)= A[MxK] @ B[NxK]^T ----
// 256 thr = 2x2 waves; wave computes (WM*16) x (WN*16); BM=32*WM, BN=32*WN, BK=32.
template<int WM, int WN, bool ACC>
__global__ __launch_bounds__(256) void k_gemm_mfma(
    const unsigned short* __restrict__ A, const unsigned short* __restrict__ B,
    float* __restrict__ C, int M, int N, int K)
{
  constexpr int BM = 32*WM, BN = 32*WN, LDT = 40;   // 32 + 8 pad (keeps 16B align)
  __shared__ unsigned short As[BM*LDT];
  __shared__ unsigned short Bs[BN*LDT];
  const int tid = threadIdx.x;
  const int bm = blockIdx.x*BM, bn = blockIdx.y*BN;
  const int w = tid >> 6, lane = tid & 63;
  const int mb = (w>>1)*WM*16, nb = (w&1)*WN*16;
  const int lr = lane & 15, lk = (lane>>4)*8;
  f32x4 acc[WM][WN] = {};
  for (int k0 = 0; k0 < K; k0 += 32) {
#pragma unroll
    for (int s = tid; s < BM*4; s += 256) {
      int row = s>>2, kg = (s&3)*8;
      *(ushort8*)&As[row*LDT+kg] = *(const ushort8*)&A[(size_t)(bm+row)*K + k0 + kg];
    }
#pragma unroll
    for (int s = tid; s < BN*4; s += 256) {
      int row = s>>2, kg = (s&3)*8;
      ushort8 v = {0,0,0,0,0,0,0,0};
      if (bn+row < N) v = *(const ushort8*)&B[(size_t)(bn+row)*K + k0 + kg];
      *(ushort8*)&Bs[row*LDT+kg] = v;
    }
    __syncthreads();
    short8 af[WM], bfr[WN];
#pragma unroll
    for (int i = 0; i < WM; ++i) af[i]  = *(const short8*)&As[(mb+i*16+lr)*LDT + lk];
#pragma unroll
    for (int j = 0; j < WN; ++j) bfr[j] = *(const short8*)&Bs[(nb+j*16+lr)*LDT + lk];
#pragma unroll
    for (int i = 0; i < WM; ++i)
#pragma unroll
      for (int j = 0; j < WN; ++j)
        acc[i][j] = __builtin_amdgcn_mfma_f32_16x16x32_bf16(af[i], bfr[j], acc[i][j], 0, 0, 0);
    __syncthreads();
  }
  // D layout: col = lane&15, row = (lane>>4)*4 + r
#pragma unroll
  for (int i = 0; i < WM; ++i) {
#pragma unroll
    for (int j = 0; j < WN; ++j) {
      int col = bn + nb + j*16 + lr;
      if (col < N) {
#pragma unroll
        for (int r = 0; r < 4; ++r) {
          int row = bm + mb + i*16 + (lane>>4)*4 + r;
          size_t o = (size_t)row*N + col;
          C[o] = ACC ? (C[o] + acc[i][j][r]) : acc[i][j][r];
        }
      }
    }
  }
}

// xc[t][e] = silu(conv(xi)[t][e]); writes fp32 (scan) + bf16 (x_proj GEMM)
__global__ void k_conv(const float* __restrict__ xz, const float* __restrict__ cw,
                       const float* __restrict__ cb, float* __restrict__ xc,
                       unsigned short* __restrict__ xcb){
  int idx = blockIdx.x*256 + threadIdx.x;  // t*512+e
  int t = idx >> 9, e = idx & 511;
  float acc = cb[e];
#pragma unroll
  for (int k = 0; k < KCONV; ++k) {
    int ts = t - (KCONV-1) + k;
    if (ts >= 0) acc += xz[ts*(2*ED) + e] * cw[e*KCONV + k];
  }
  float v = siluf_(acc);
  xc[idx] = v;
  xcb[idx] = f2bf(v);
}

// Phase 1 (dt_proj fused): per chunk c, per e: S = sum delta; Q = local scan end (h0=0)
__global__ __launch_bounds__(256) void k_scan1(
    const float* __restrict__ xc, const float* __restrict__ dbc,
    const float* __restrict__ dtw, const float* __restrict__ dtb,
    const float* __restrict__ alog, float* __restrict__ S, float* __restrict__ Q){
  __shared__ float Ds[CHUNK][DT_RANK];
  __shared__ float Bsh[CHUNK][NSTATE];
  int c = blockIdx.x >> 1;
  int e = (blockIdx.x & 1)*256 + threadIdx.x;
  int t0 = c*CHUNK;
  for (int i = threadIdx.x; i < CHUNK*48; i += 256) {
    int t = i/48, col = i - t*48;
    float v = dbc[(t0+t)*48 + col];
    if (col < DT_RANK) Ds[t][col] = v;
    else if (col < DT_RANK+NSTATE) Bsh[t][col-DT_RANK] = v;
  }
  __syncthreads();
  float dtwv[DT_RANK];
#pragma unroll
  for (int r = 0; r < DT_RANK; ++r) dtwv[r] = dtw[e*DT_RANK+r];
  float dtbv = dtb[e];
  float x[CHUNK];
#pragma unroll
  for (int t = 0; t < CHUNK; ++t) x[t] = xc[(t0+t)*ED + e];
  float A[NSTATE];
#pragma unroll
  for (int n = 0; n < NSTATE; ++n) A[n] = -__expf(alog[e*NSTATE+n]);
  float h[NSTATE] = {};
  float sd = 0.f;
#pragma unroll
  for (int t = 0; t < CHUNK; ++t) {
    float da = dtbv;
#pragma unroll
    for (int r = 0; r < DT_RANK; ++r) da += Ds[t][r]*dtwv[r];
    float d = softplusf_(da);
    sd += d;
    float dx = d*x[t];
#pragma unroll
    for (int n = 0; n < NSTATE; ++n)
      h[n] = __expf(d*A[n])*h[n] + dx*Bsh[t][n];
  }
  S[c*ED + e] = sd;
#pragma unroll
  for (int n = 0; n < NSTATE; ++n) Q[(c*NSTATE+n)*ED + e] = h[n];
}

// Phase 2: sequential over 256 chunks, parallel over 8192 (n,e) channels.
// In-place: Q[c] (local end state) is replaced by Hin[c] (true state BEFORE chunk c).
__global__ void k_scan2(const float* __restrict__ alog, const float* __restrict__ S,
                        float* __restrict__ Q){
  int ch = blockIdx.x*256 + threadIdx.x;  // n*512 + e
  int n = ch >> 9, e = ch & 511;
  float a = -__expf(alog[e*NSTATE+n]);
  float h = 0.f;
  for (int g = 0; g < NCHUNK/8; ++g) {
    float sv[8], qv[8], ev[8];
#pragma unroll
    for (int k = 0; k < 8; ++k) sv[k] = S[(g*8+k)*ED + e];
#pragma unroll
    for (int k = 0; k < 8; ++k) qv[k] = Q[((g*8+k)*NSTATE+n)*ED + e];
#pragma unroll
    for (int k = 0; k < 8; ++k) ev[k] = __expf(a*sv[k]);
#pragma unroll
    for (int k = 0; k < 8; ++k) {
      Q[((g*8+k)*NSTATE+n)*ED + e] = h;
      h = ev[k]*h + qv[k];
    }
  }
}

// Phase 3: replay chunk with true Hin; fuse dt_proj, C-dot, D-skip, silu(z) gate; bf16 y.
__global__ __launch_bounds__(256) void k_scan3(
    const float* __restrict__ xc, const float* __restrict__ dbc,
    const float* __restrict__ dtw, const float* __restrict__ dtb,
    const float* __restrict__ alog, const float* __restrict__ Hin,
    const float* __restrict__ xz, const float* __restrict__ Dv,
    unsigned short* __restrict__ y){
  __shared__ float Ds[CHUNK][DT_RANK];
  __shared__ float Bsh[CHUNK][NSTATE];
  __shared__ float Cs[CHUNK][NSTATE];
  int c = blockIdx.x >> 1;
  int e = (blockIdx.x & 1)*256 + threadIdx.x;
  int t0 = c*CHUNK;
  for (int i = threadIdx.x; i < CHUNK*48; i += 256) {
    int t = i/48, col = i - t*48;
    float v = dbc[(t0+t)*48 + col];
    if (col < DT_RANK) Ds[t][col] = v;
    else if (col < DT_RANK+NSTATE) Bsh[t][col-DT_RANK] = v;
    else Cs[t][col-DT_RANK-NSTATE] = v;
  }
  __syncthreads();
  float dtwv[DT_RANK];
#pragma unroll
  for (int r = 0; r < DT_RANK; ++r) dtwv[r] = dtw[e*DT_RANK+r];
  float dtbv = dtb[e];
  float x[CHUNK], z[CHUNK];
#pragma unroll
  for (int t = 0; t < CHUNK; ++t) x[t] = xc[(t0+t)*ED + e];
#pragma unroll
  for (int t = 0; t < CHUNK; ++t) z[t] = xz[(t0+t)*(2*ED) + ED + e];
  float A[NSTATE], h[NSTATE];
#pragma unroll
  for (int n = 0; n < NSTATE; ++n) {
    A[n] = -__expf(alog[e*NSTATE+n]);
    h[n] = Hin[(c*NSTATE+n)*ED + e];
  }
  float dv = Dv[e];
#pragma unroll
  for (int t = 0; t < CHUNK; ++t) {
    float da = dtbv;
#pragma unroll
    for (int r = 0; r < DT_RANK; ++r) da += Ds[t][r]*dtwv[r];
    float d = softplusf_(da);
    float dx = d*x[t];
    float ysum = 0.f;
#pragma unroll
    for (int n = 0; n < NSTATE; ++n) {
      h[n] = __expf(d*A[n])*h[n] + dx*Bsh[t][n];
      ysum += h[n]*Cs[t][n];
    }
    y[(t0+t)*ED + e] = f2bf((ysum + dv*x[t]) * siluf_(z[t]));
  }
}

// out[t] = tanh( h[t][:] . fc_out_w + fc_out_b ) — one wave per row
__global__ void k_fc_out(const float* __restrict__ h, const float* __restrict__ w,
                         const float* __restrict__ b, float* __restrict__ out){
  int wave = threadIdx.x >> 6, lane = threadIdx.x & 63;
  int row = blockIdx.x*4 + wave;
  const float4 hv = *(const float4*)&h[row*D_MODEL + lane*4];
  const float4 wv = *(const float4*)&w[lane*4];
  float s = hv.x*wv.x + hv.y*wv.y + hv.z*wv.z + hv.w*wv.w;
#pragma unroll
  for (int m = 32; m; m >>= 1) s += __shfl_xor(s, m);
  if (lane == 0) out[row] = tanhf(s + b[0]);
}

extern "C" void kernel_launch(void* const* d_in, const int* in_sizes, int n_in,
                              void* d_out, int out_size, void* d_ws, size_t ws_size,
                              hipStream_t stream){
  const float* x    = (const float*)d_in[0];
  const float* fiw  = (const float*)d_in[1];
  const float* fib  = (const float*)d_in[2];
  const float* fow  = (const float*)d_in[3];
  const float* fob  = (const float*)d_in[4];
  const float* nw   = (const float*)d_in[5];
  const float* ipw  = (const float*)d_in[6];
  const float* cw   = (const float*)d_in[7];
  const float* cb   = (const float*)d_in[8];
  const float* xpw  = (const float*)d_in[9];
  const float* dtw  = (const float*)d_in[10];
  const float* dtb  = (const float*)d_in[11];
  const float* alog = (const float*)d_in[12];
  const float* Dv   = (const float*)d_in[13];
  const float* opw  = (const float*)d_in[14];

  float* W = (float*)d_ws;
  float* h    = W;                                   // L*256
  float* xz   = h    + (size_t)LSEQ*D_MODEL;         // L*1024
  float* xc   = xz   + (size_t)LSEQ*2*ED;            // L*512
  float* dbc  = xc   + (size_t)LSEQ*ED;              // L*48
  float* S    = dbc  + (size_t)LSEQ*48;              // 256*512
  float* Q    = S    + (size_t)NCHUNK*ED;            // 256*16*512 (becomes Hin in-place)
  unsigned short* xn  = (unsigned short*)(Q + (size_t)NCHUNK*NSTATE*ED); // L*256
  unsigned short* xcb = xn  + (size_t)LSEQ*D_MODEL;  // L*512
  unsigned short* yb  = xcb + (size_t)LSEQ*ED;       // L*512
  unsigned short* wip = yb  + (size_t)LSEQ*ED;       // 2*1024*256
  unsigned short* wxp = wip + (size_t)2*2*ED*D_MODEL;// 2*48*512
  unsigned short* wop = wxp + (size_t)2*48*ED;       // 2*256*512

  k_wconv<<<(2*2*ED*D_MODEL)/256, 256, 0, stream>>>(ipw, xpw, opw, wip, wxp, wop);
  k_fc_in<<<LSEQ*D_MODEL/256, 256, 0, stream>>>(x, fiw, fib, h);

  for (int l = 0; l < 2; ++l) {
    const unsigned short* wip_l = wip + (size_t)l*2*ED*D_MODEL;
    const unsigned short* wxp_l = wxp + (size_t)l*48*ED;
    const unsigned short* wop_l = wop + (size_t)l*D_MODEL*ED;
    const float* nw_l   = nw   + l*D_MODEL;
    const float* cw_l   = cw   + l*ED*KCONV;
    const float* cb_l   = cb   + l*ED;
    const float* dtw_l  = dtw  + l*ED*DT_RANK;
    const float* dtb_l  = dtb  + l*ED;
    const float* alog_l = alog + l*ED*NSTATE;
    const float* D_l    = Dv   + l*ED;

    k_rmsapply<<<LSEQ/4, 256, 0, stream>>>(h, nw_l, xn);
    k_gemm_mfma<4,4,false><<<dim3(LSEQ/128, (2*ED)/128), 256, 0, stream>>>(
        xn, wip_l, xz, LSEQ, 2*ED, D_MODEL);
    k_conv<<<LSEQ*ED/256, 256, 0, stream>>>(xz, cw_l, cb_l, xc, xcb);
    k_gemm_mfma<2,2,false><<<dim3(LSEQ/64, 1), 256, 0, stream>>>(
        xcb, wxp_l, dbc, LSEQ, 48, ED);
    k_scan1<<<NCHUNK*2, 256, 0, stream>>>(xc, dbc, dtw_l, dtb_l, alog_l, S, Q);
    k_scan2<<<ED*NSTATE/256, 256, 0, stream>>>(alog_l, S, Q);
    k_scan3<<<NCHUNK*2, 256, 0, stream>>>(xc, dbc, dtw_l, dtb_l, alog_l, Q, xz, D_l, yb);
    k_gemm_mfma<2,2,true ><<<dim3(LSEQ/64, D_MODEL/64), 256, 0, stream>>>(
        yb, wop_l, h, LSEQ, D_MODEL, ED);
  }

  k_fc_out<<<LSEQ/4, 256, 0, stream>>>(h, fow, fob, (float*)d_out);
}